// Round 5
// baseline (683.571 us; speedup 1.0000x reference)
//
#include <hip/hip_runtime.h>
#include <stdint.h>

// Scatter-upsample, numpy last-write-wins:
//   y = zeros((num_nodes,256)); y[col(k), row(k)] = x.flat[k]  (largest k wins)
//   col(k) = neigh[7*i + max_index[i,f]], k = i*256+f, row(k)=floor(k*256/(T-1)).
//
// R4 post-mortem: role-split helped (336->287) but the per-window LDS-hash
// build chain is still the ~90us long pole. This version removes the hash:
//   K1: wave-per-node build (4 coalesced mi loads + 28 ballots, all-register,
//       no LDS) emits ALL candidates (slot, k+1, xbits) to d_ws, while 1024
//       zeroer WGs write the 168MB zero concurrently at full BW.
//   K2: tag pass — atomicMax(out_int[slot], k+1). Distinct k per entry =>
//       unique winner per slot; untagged slots keep int 0 == 0.0f.
//   K3: value pass — winner (tag matches) overwrites tag with float bits.
// Stream order between kernels is the global barrier. Row-straddling nodes
// (~255/40962, node's 256 k's cross a row boundary) emit lo+hi segment
// candidates on lanes 0-6 / 8-14.

#define FEAT 256
#define LOG2FEAT 8
#define BLOCK 256
#define BUILD_WGS 256          // 1024 builder waves, ~40 nodes each
#define ZERO_WGS 1024          // 262144 zeroer threads
#define ENTRY_CAP (1 << 19)    // 512K int4 entries = 8 MB (need ~289K)

extern "C" __global__ __launch_bounds__(BLOCK)
void build_zero_kernel(const float* __restrict__ x,     // f32 (bf16-rounded)
                       const int*   __restrict__ mi,    // int32 0..6
                       const int*   __restrict__ neigh, // int32
                       float*       __restrict__ out,
                       int*         __restrict__ cursor,  // ws+0
                       int4*        __restrict__ entries, // ws+16
                       int total,                          // raw_nodes*256
                       int out_elems)                      // num_nodes*256
{
    const int tid = threadIdx.x;

    // ---- zeroer role: saturate HBM write BW while builders run ------------
    if (blockIdx.x >= BUILD_WGS) {
        const int zid = blockIdx.x - BUILD_WGS;
        float4* out4 = (float4*)out;
        const int total4 = out_elems >> 2;               // exact multiple of 4
        const float4 z = make_float4(0.f, 0.f, 0.f, 0.f);
        for (int idx = zid * BLOCK + tid; idx < total4; idx += ZERO_WGS * BLOCK)
            out4[idx] = z;
        return;
    }

    // ---- builder role: one wave per node, all-register ---------------------
    const int lane      = tid & 63;
    const int wv        = (blockIdx.x * BLOCK + tid) >> 6;   // global wave id
    const int nwaves    = BUILD_WGS * (BLOCK / 64);
    const int raw_nodes = total >> LOG2FEAT;
    const unsigned tm1  = (unsigned)(total - 1);

    for (int i = wv; i < raw_nodes; i += nwaves) {
        const int kbase = i << LOG2FEAT;
        const int* mrow = mi + kbase;
        // 4 coalesced 256B loads: lane l covers f = j*64 + l
        const int m0 = mrow[lane];
        const int m1 = mrow[64 + lane];
        const int m2 = mrow[128 + lane];
        const int m3 = mrow[192 + lane];

        unsigned long long b[4][7];
        #pragma unroll
        for (int m = 0; m < 7; ++m) {
            b[0][m] = __ballot(m0 == m);
            b[1][m] = __ballot(m1 == m);
            b[2][m] = __ballot(m2 == m);
            b[3][m] = __ballot(m3 == m);
        }

        // rows this node touches (spans at most one boundary: window ~40961 k)
        unsigned r_first = (((unsigned)kbase) << 8) / tm1;
        unsigned r_last  = (((unsigned)(kbase + FEAT - 1)) << 8) / tm1;
        if (r_last > 255u) r_last = 255u;                 // k=T-1 clamp
        const bool straddle = (r_last != r_first);
        unsigned fb = FEAT;                               // lo segment: f < fb
        if (straddle) fb = ((r_last * tm1 + 255u) >> 8) - (unsigned)kbase;

        // uniform lo-segment masks per group
        unsigned long long g[4];
        #pragma unroll
        for (int j = 0; j < 4; ++j)
            g[j] = (fb >= (unsigned)(j + 1) * 64) ? ~0ull
                 : (fb <= (unsigned)j * 64)       ? 0ull
                 : ((1ull << (fb - (unsigned)j * 64)) - 1ull);

        // lanes 0-6: m=lane, lo segment; lanes 8-14: m=lane-8, hi segment
        int  m  = -1;
        bool hi = false;
        if (lane < 7)                                { m = lane;     hi = false; }
        else if (straddle && lane >= 8 && lane < 15) { m = lane - 8; hi = true;  }

        bool found = false;
        int slot = 0, kp1 = 0, vbits = 0;
        if (m >= 0) {
            int bestf = -1;
            #pragma unroll
            for (int j = 3; j >= 0; --j) {
                if (bestf < 0) {
                    unsigned long long s =
                        (m == 0) ? b[j][0] : (m == 1) ? b[j][1] :
                        (m == 2) ? b[j][2] : (m == 3) ? b[j][3] :
                        (m == 4) ? b[j][4] : (m == 5) ? b[j][5] : b[j][6];
                    unsigned long long t = s & (hi ? ~g[j] : g[j]);
                    if (t) bestf = j * 64 + 63 - __clzll(t);
                }
            }
            if (bestf >= 0) {
                const int k   = kbase + bestf;
                const int col = neigh[i * 7 + m];
                const int r   = hi ? (int)r_last : (int)r_first;
                slot  = (col << LOG2FEAT) | r;
                kp1   = k + 1;                            // tag > 0 always
                vbits = __float_as_int(x[k]);
                found = true;
            }
        }

        // wave-compact emission: one atomicAdd per node
        const unsigned long long em = __ballot(found);
        if (em) {
            const int leader = __ffsll(em) - 1;
            const int rank   = __popcll(em & ((1ull << lane) - 1ull));
            int base = 0;
            if (lane == leader) base = atomicAdd(cursor, __popcll(em));
            base = __shfl(base, leader);
            if (found) {
                const int pos = base + rank;
                if (pos < ENTRY_CAP)
                    entries[pos] = make_int4(slot, kp1, vbits, 0);
            }
        }
    }
}

extern "C" __global__ __launch_bounds__(256)
void tag_kernel(int* __restrict__ out_i,
                const int*  __restrict__ cursor,
                const int4* __restrict__ entries)
{
    int n = *cursor;
    if (n > ENTRY_CAP) n = ENTRY_CAP;
    for (int idx = blockIdx.x * 256 + threadIdx.x; idx < n; idx += gridDim.x * 256) {
        const int4 e = entries[idx];
        atomicMax(out_i + e.x, e.y);                      // winner = max k+1
    }
}

extern "C" __global__ __launch_bounds__(256)
void value_kernel(int* __restrict__ out_i,
                  const int*  __restrict__ cursor,
                  const int4* __restrict__ entries)
{
    int n = *cursor;
    if (n > ENTRY_CAP) n = ENTRY_CAP;
    for (int idx = blockIdx.x * 256 + threadIdx.x; idx < n; idx += gridDim.x * 256) {
        const int4 e = entries[idx];
        if (out_i[e.x] == e.y) out_i[e.x] = e.z;          // winner writes bits
    }
}

extern "C" void kernel_launch(void* const* d_in, const int* in_sizes, int n_in,
                              void* d_out, int out_size, void* d_ws, size_t ws_size,
                              hipStream_t stream) {
    const float* x     = (const float*)d_in[0];   // f32 (40962, 256)
    const int*   mi    = (const int*)d_in[1];     // int32 (40962, 256), 0..6
    const int*   neigh = (const int*)d_in[2];     // int32 (40962*7,)
    float*       out   = (float*)d_out;

    const int total     = in_sizes[0];            // raw_nodes * 256
    const int out_elems = out_size;               // num_nodes * 256

    int*  cursor  = (int*)d_ws;
    int4* entries = (int4*)((char*)d_ws + 16);

    hipMemsetAsync(d_ws, 0, 16, stream);          // zero the emission cursor

    build_zero_kernel<<<dim3(BUILD_WGS + ZERO_WGS), dim3(BLOCK), 0, stream>>>(
        x, mi, neigh, out, cursor, entries, total, out_elems);
    tag_kernel<<<dim3(512), dim3(256), 0, stream>>>((int*)out, cursor, entries);
    value_kernel<<<dim3(512), dim3(256), 0, stream>>>((int*)out, cursor, entries);
}

// Round 6
// 281.335 us; speedup vs baseline: 2.4297x; 2.4297x over previous
//
#include <hip/hip_runtime.h>
#include <stdint.h>

// Scatter-upsample, numpy last-write-wins:
//   y = zeros((num_nodes,256)); y[col(k), row(k)] = x.flat[k]  (largest k wins)
//   col(k) = neigh[7*i + max_index[i,f]], k = i*256+f, row(k)=floor(k*256/(T-1)).
//
// R5 post-mortem: the single global atomicAdd emission cursor (40962
// same-address device-scope RMWs with return dependence, cross-XCD) was a
// ~400us serial chain (474us kernel, 2.5% VALU, 5% HBM). Fix: NO atomics in
// the build at all — deterministic emission layout, 16 int2 slots per node:
//   lane 0-6  -> lo-segment candidate for m=lane   (kp1=0 if none)
//   lane 8-14 -> hi-segment candidate for m=lane-8 (only when row-straddling)
//   lanes 7,15 -> padding (kp1=0)
// K1: wave-per-node register build (4 coalesced mi loads + 28 ballots) +
//     concurrent zeroer WGs writing the 168MB output at full BW.
// K2: tag — scan entries, atomicMax(out_i[slot], kp1) (distinct slots, no
//     contention). Untagged slots keep int 0 == 0.0f.
// K3: value — winner (tag==kp1) overwrites tag with x[kp1-1] bits.
// All kp1 are globally distinct => exactly one winner per slot.

#define FEAT 256
#define LOG2FEAT 8
#define BLOCK 256
#define BUILD_WGS 256          // 1024 builder waves, ~40 nodes each
#define ZERO_WGS 1024
#define EPN 16                 // entry slots per node

extern "C" __global__ __launch_bounds__(BLOCK)
void build_zero_kernel(const int*   __restrict__ mi,    // int32 0..6
                       const int*   __restrict__ neigh, // int32
                       float*       __restrict__ out,
                       int2*        __restrict__ entries, // [raw_nodes*EPN]
                       int total,                          // raw_nodes*256
                       int out_elems)                      // num_nodes*256
{
    const int tid = threadIdx.x;

    // ---- zeroer role: saturate HBM write BW while builders run ------------
    if (blockIdx.x >= BUILD_WGS) {
        const int zid = blockIdx.x - BUILD_WGS;
        float4* out4 = (float4*)out;
        const int total4 = out_elems >> 2;               // exact multiple of 4
        const float4 z = make_float4(0.f, 0.f, 0.f, 0.f);
        for (int idx = zid * BLOCK + tid; idx < total4; idx += ZERO_WGS * BLOCK)
            out4[idx] = z;
        return;
    }

    // ---- builder role: one wave per node, all-register, ZERO atomics ------
    const int lane      = tid & 63;
    const int wv        = (blockIdx.x * BLOCK + tid) >> 6;   // global wave id
    const int nwaves    = BUILD_WGS * (BLOCK / 64);
    const int raw_nodes = total >> LOG2FEAT;
    const unsigned tm1  = (unsigned)(total - 1);

    // software pipeline: prefetch node wv's mi row
    int p0 = 0, p1 = 0, p2 = 0, p3 = 0;
    if (wv < raw_nodes) {
        const int* mrow = mi + (wv << LOG2FEAT);
        p0 = mrow[lane]; p1 = mrow[64 + lane];
        p2 = mrow[128 + lane]; p3 = mrow[192 + lane];
    }

    for (int i = wv; i < raw_nodes; i += nwaves) {
        const int m0 = p0, m1 = p1, m2 = p2, m3 = p3;
        const int i_n = i + nwaves;
        if (i_n < raw_nodes) {                            // prefetch next node
            const int* mrow = mi + (i_n << LOG2FEAT);
            p0 = mrow[lane]; p1 = mrow[64 + lane];
            p2 = mrow[128 + lane]; p3 = mrow[192 + lane];
        }

        const int kbase = i << LOG2FEAT;
        unsigned long long b[4][7];
        #pragma unroll
        for (int m = 0; m < 7; ++m) {
            b[0][m] = __ballot(m0 == m);
            b[1][m] = __ballot(m1 == m);
            b[2][m] = __ballot(m2 == m);
            b[3][m] = __ballot(m3 == m);
        }

        // rows this node touches (spans at most one boundary)
        unsigned r_first = (((unsigned)kbase) << 8) / tm1;
        unsigned r_last  = (((unsigned)(kbase + FEAT - 1)) << 8) / tm1;
        if (r_last > 255u) r_last = 255u;                 // k=T-1 clamp
        const bool straddle = (r_last != r_first);
        unsigned fb = FEAT;                               // lo segment: f < fb
        if (straddle) fb = ((r_last * tm1 + 255u) >> 8) - (unsigned)kbase;

        unsigned long long g[4];
        #pragma unroll
        for (int j = 0; j < 4; ++j)
            g[j] = (fb >= (unsigned)(j + 1) * 64) ? ~0ull
                 : (fb <= (unsigned)j * 64)       ? 0ull
                 : ((1ull << (fb - (unsigned)j * 64)) - 1ull);

        // lanes 0-6: m=lane, lo segment; lanes 8-14: m=lane-8, hi segment
        int  m  = -1;
        bool hi = false;
        if (lane < 7)                                { m = lane;     hi = false; }
        else if (straddle && lane >= 8 && lane < 15) { m = lane - 8; hi = true;  }

        int2 ent = make_int2(0, 0);                       // kp1=0 == invalid
        if (m >= 0) {
            int bestf = -1;
            #pragma unroll
            for (int j = 3; j >= 0; --j) {
                if (bestf < 0) {
                    unsigned long long s =
                        (m == 0) ? b[j][0] : (m == 1) ? b[j][1] :
                        (m == 2) ? b[j][2] : (m == 3) ? b[j][3] :
                        (m == 4) ? b[j][4] : (m == 5) ? b[j][5] : b[j][6];
                    unsigned long long t = s & (hi ? ~g[j] : g[j]);
                    if (t) bestf = j * 64 + 63 - __clzll(t);
                }
            }
            if (bestf >= 0) {
                const int k   = kbase + bestf;
                const int col = neigh[i * 7 + m];         // 7 ints, 1 line
                const int r   = hi ? (int)r_last : (int)r_first;
                ent = make_int2((col << LOG2FEAT) | r, k + 1);
            }
        }
        if (lane < EPN)                                   // 128B coalesced
            entries[(size_t)i * EPN + lane] = ent;
    }
}

extern "C" __global__ __launch_bounds__(256)
void tag_kernel(int* __restrict__ out_i,
                const int2* __restrict__ entries,
                int n_entries)
{
    for (int idx = blockIdx.x * 256 + threadIdx.x; idx < n_entries;
         idx += gridDim.x * 256) {
        const int2 e = entries[idx];
        if (e.y > 0) atomicMax(out_i + e.x, e.y);         // winner = max k+1
    }
}

extern "C" __global__ __launch_bounds__(256)
void value_kernel(int* __restrict__ out_i,
                  const float* __restrict__ x,
                  const int2* __restrict__ entries,
                  int n_entries)
{
    for (int idx = blockIdx.x * 256 + threadIdx.x; idx < n_entries;
         idx += gridDim.x * 256) {
        const int2 e = entries[idx];
        if (e.y > 0 && out_i[e.x] == e.y)
            out_i[e.x] = __float_as_int(x[e.y - 1]);      // winner writes bits
    }
}

extern "C" void kernel_launch(void* const* d_in, const int* in_sizes, int n_in,
                              void* d_out, int out_size, void* d_ws, size_t ws_size,
                              hipStream_t stream) {
    const float* x     = (const float*)d_in[0];   // f32 (40962, 256)
    const int*   mi    = (const int*)d_in[1];     // int32 (40962, 256), 0..6
    const int*   neigh = (const int*)d_in[2];     // int32 (40962*7,)
    float*       out   = (float*)d_out;

    const int total     = in_sizes[0];            // raw_nodes * 256
    const int out_elems = out_size;               // num_nodes * 256
    const int raw_nodes = total >> LOG2FEAT;
    const int n_entries = raw_nodes * EPN;        // 655392 (5.2 MB of int2)

    int2* entries = (int2*)d_ws;

    build_zero_kernel<<<dim3(BUILD_WGS + ZERO_WGS), dim3(BLOCK), 0, stream>>>(
        mi, neigh, out, entries, total, out_elems);
    tag_kernel<<<dim3(1024), dim3(256), 0, stream>>>(
        (int*)out, entries, n_entries);
    value_kernel<<<dim3(1024), dim3(256), 0, stream>>>(
        (int*)out, x, entries, n_entries);
}